// Round 3
// baseline (437.897 us; speedup 1.0000x reference)
//
#include <hip/hip_runtime.h>
#include <math.h>

// N=5, B=8, C=256, H*W=1024
#define NN 5
#define CC 256
#define SSP 1024
#define BB 8
#define THRESHV 0.3f

typedef __attribute__((ext_vector_type(8))) short short8;   // 8 bf16 = one MFMA A/B frag
typedef __attribute__((ext_vector_type(4))) float f32x4;    // MFMA 16x16 accumulator

// ---------------- ws layout (bytes) ----------------
// X split planes, k-minor: [(j*8+b)*3+sp][s:1024][k:256] bf16
#define XW_OFF   0ull
#define XW_PLANE ((size_t)SSP * CC * 2)                 // 524288
#define XW_SIZE  ((size_t)NN * BB * 3 * XW_PLANE)       // 62,914,560
// A = W1+W2 split planes, k-minor: [i*3+sp][o:256][k:256]
#define AW_OFF   XW_SIZE
#define AW_PLANE ((size_t)CC * CC * 2)                  // 131072
#define AW_SIZE  ((size_t)NN * 3 * AW_PLANE)            // 1,966,080
#define W2_OFF   (AW_OFF + AW_SIZE)
#define WS_NEED  (W2_OFF + AW_SIZE)                     // ~63.8 MiB

// ---- exact 3-way bf16 split (Dekker-style; residuals exact in fp32) ----
static __device__ __forceinline__ unsigned short f2bf(float f) {
    unsigned int u = __builtin_bit_cast(unsigned int, f);
    u = u + 0x7fffu + ((u >> 16) & 1u);          // RNE to bf16
    return (unsigned short)(u >> 16);
}
static __device__ __forceinline__ float bf2f(unsigned short h) {
    unsigned int u = ((unsigned int)h) << 16;
    return __builtin_bit_cast(float, u);
}
static __device__ __forceinline__ void split3(float a, unsigned short& h,
                                              unsigned short& m, unsigned short& l) {
    h = f2bf(a); float r1 = a - bf2f(h);
    m = f2bf(r1); float r2 = r1 - bf2f(m);
    l = f2bf(r2);
}
static __device__ __forceinline__ f32x4 MF(short8 a, short8 b, f32x4 c) {
    return __builtin_amdgcn_mfma_f32_16x16x32_bf16(a, b, c, 0, 0, 0);
}

// async global->LDS, 16B per lane; LDS dest = uniform base + lane*16
#define GLD16(gp, lp) __builtin_amdgcn_global_load_lds(                          \
        (const __attribute__((address_space(1))) unsigned int*)(gp),             \
        (__attribute__((address_space(3))) unsigned int*)(lp), 16, 0, 0)

// ================= pre-pass: split weights =================
__global__ __launch_bounds__(256)
void prep_w(const float* __restrict__ w, unsigned char* __restrict__ ws) {
    const int id = blockIdx.x * 256 + threadIdx.x;   // 40960 = 5*256*32
    const int i  = id >> 13;
    const int o  = (id >> 5) & 255;
    const int ko = id & 31;                          // k-oct
    const float* gw = w + (size_t)(i * CC + o) * (2 * CC) + ko * 8;
    float av[8], wv[8];
    #pragma unroll
    for (int kk = 0; kk < 8; kk++) {
        wv[kk] = gw[CC + kk];
        av[kk] = gw[kk] + wv[kk];
    }
    unsigned short h[8], m[8], l[8];
    short8 H, M, L;
    // A planes
    #pragma unroll
    for (int kk = 0; kk < 8; kk++) split3(av[kk], h[kk], m[kk], l[kk]);
    #pragma unroll
    for (int kk = 0; kk < 8; kk++) { H[kk] = (short)h[kk]; M[kk] = (short)m[kk]; L[kk] = (short)l[kk]; }
    {
        unsigned char* p = ws + AW_OFF + (size_t)((i * 3) * CC + o) * 512 + ko * 16;
        *(short8*)(p)                = H;
        *(short8*)(p + CC * 512)     = M;   // sp=1 plane (+CC rows)
        *(short8*)(p + 2 * CC * 512) = L;
    }
    // W2 planes
    #pragma unroll
    for (int kk = 0; kk < 8; kk++) split3(wv[kk], h[kk], m[kk], l[kk]);
    #pragma unroll
    for (int kk = 0; kk < 8; kk++) { H[kk] = (short)h[kk]; M[kk] = (short)m[kk]; L[kk] = (short)l[kk]; }
    {
        unsigned char* p = ws + W2_OFF + (size_t)((i * 3) * CC + o) * 512 + ko * 16;
        *(short8*)(p)                = H;
        *(short8*)(p + CC * 512)     = M;
        *(short8*)(p + 2 * CC * 512) = L;
    }
}

// ================= pre-pass: split + transpose x =================
__global__ __launch_bounds__(256)
void prep_x(const float* __restrict__ x, unsigned char* __restrict__ ws) {
    const int blk = blockIdx.x;          // 320 = 40 jb * 8 k-chunks
    const int kc  = blk & 7;
    const int jb  = blk >> 3;            // j*8+b
    const int k0  = kc * 32;
    const int t   = threadIdx.x;
    #pragma unroll 1
    for (int r = 0; r < 4; r++) {
        const int s = t + 256 * r;
        const float* gx = x + ((size_t)jb * CC + k0) * SSP + s;
        unsigned char* w0 = ws + XW_OFF + (size_t)(jb * 3) * XW_PLANE
                          + (size_t)s * 512 + (size_t)k0 * 2;
        #pragma unroll
        for (int oct = 0; oct < 4; oct++) {
            float v[8];
            #pragma unroll
            for (int kk = 0; kk < 8; kk++) v[kk] = gx[(size_t)(oct * 8 + kk) * SSP];
            unsigned short h[8], m[8], l[8];
            #pragma unroll
            for (int kk = 0; kk < 8; kk++) split3(v[kk], h[kk], m[kk], l[kk]);
            short8 H, M, L;
            #pragma unroll
            for (int kk = 0; kk < 8; kk++) { H[kk] = (short)h[kk]; M[kk] = (short)m[kk]; L[kk] = (short)l[kk]; }
            *(short8*)(w0 + oct * 16)                 = H;
            *(short8*)(w0 + XW_PLANE + oct * 16)      = M;
            *(short8*)(w0 + 2 * XW_PLANE + oct * 16)  = L;
        }
    }
}

// ================= main fused kernel =================
// LDS: 3840 units of 16B; unit g at byte g*16.
//   A planes (i*3+sp): g in [0,1920)   -> plane p = g>>7, u = g&127
//   X planes (j*3+sp): g in [1920,3840)
// Within a plane: u = row*4 + (oct ^ (row&3) ^ ((row>>2)&3))  [bank swizzle via gaddr]
__global__ __launch_bounds__(512, 2)
void fub_main(const float* __restrict__ x, const float* __restrict__ bias,
              const unsigned char* __restrict__ ws, float* __restrict__ out)
{
    __shared__ unsigned short S[30720];   // 61440 B
    char* SB = (char*)S;

    const int tid  = threadIdx.x;
    const int b    = blockIdx.z;
    const int o0   = blockIdx.y * 32;
    const int s0   = blockIdx.x * 32;
    const int lane = tid & 63;
    const int wv   = tid >> 6;
    const int q    = wv & 3;
    const int oh   = q >> 1, sh = q & 1;
    const int iset = wv >> 2;
    const int qd   = lane >> 4;
    const int m_   = lane & 15;
    const int ar   = 16 * oh + m_;        // local o row 0..31
    const int xr   = 16 * sh + m_;        // local s row 0..31

    // ---- staging slots: 60 DMA instrs over 8 waves (8,8,8,8,7,7,7,7) ----
    int sbase, nslots;
    if (wv < 4) { sbase = wv * 8;            nslots = 8; }
    else        { sbase = 32 + (wv - 4) * 7; nslots = 7; }
    unsigned soff[8];
    #pragma unroll
    for (int t = 0; t < 8; t++) {
        if (t < nslots) {
            const int g = (sbase + t) * 64 + lane;
            unsigned off;
            if (g < 1920) {
                const int p = g >> 7, u = g & 127;
                const int o = u >> 2, oct = (u & 3) ^ (o & 3) ^ ((o >> 2) & 3);
                off = (unsigned)AW_OFF + (unsigned)(p * CC + o0 + o) * 512u + oct * 16u;
            } else {
                const int gg = g - 1920, p = gg >> 7, u = gg & 127;
                const int s = u >> 2, oct = (u & 3) ^ (s & 3) ^ ((s >> 2) & 3);
                const int j = p / 3, sp = p % 3;
                off = (unsigned)(((j * BB + b) * 3 + sp) * SSP + s0 + s) * 512u + oct * 16u;
            }
            soff[t] = off;
        } else soff[t] = 0;
    }

    // ---- W2 frag base offsets (direct global->register) ----
    unsigned w2off[9];
    {
        const int IB = iset ? 2 : 0;
        #pragma unroll
        for (int ii = 0; ii < 3; ii++)
            #pragma unroll
            for (int sp = 0; sp < 3; sp++)
                w2off[ii * 3 + sp] = (unsigned)W2_OFF
                    + (unsigned)(((IB + ii) * 3 + sp) * CC + o0 + ar) * 512u + qd * 16u;
    }

    // ---- LDS frag read byte offsets (within-plane, swizzled) ----
    const unsigned abyte = (unsigned)(ar * 4 + (qd ^ (ar & 3) ^ ((ar >> 2) & 3))) * 16u;
    const unsigned xbyte = 30720u + (unsigned)(xr * 4 + (qd ^ (xr & 3) ^ ((xr >> 2) & 3))) * 16u;

    f32x4 accY[3][5];
    f32x4 accU[3];
    #pragma unroll
    for (int ii = 0; ii < 3; ii++) {
        accU[ii] = (f32x4){0.f, 0.f, 0.f, 0.f};
        #pragma unroll
        for (int j = 0; j < NN; j++) accY[ii][j] = (f32x4){0.f, 0.f, 0.f, 0.f};
    }

    #pragma unroll 1
    for (int k0 = 0; k0 < CC; k0 += 32) {
        if (k0) __syncthreads();
        // stage A + X via DMA (per-lane gaddr carries the swizzle)
        #pragma unroll
        for (int t = 0; t < 8; t++) {
            if (t < nslots) {
                GLD16(ws + soff[t], SB + (sbase + t) * 1024);
                soff[t] += 64;
            }
        }
        // W2 frags -> registers (latency hidden under barrier + Y phase)
        short8 w2f[3][3];
        if (iset == 0) {
            #pragma unroll
            for (int ii = 0; ii < 2; ii++)
                #pragma unroll
                for (int sp = 0; sp < 3; sp++)
                    w2f[ii][sp] = *(const short8*)(ws + w2off[ii * 3 + sp] + (unsigned)k0 * 2);
        } else {
            #pragma unroll
            for (int ii = 0; ii < 3; ii++)
                #pragma unroll
                for (int sp = 0; sp < 3; sp++)
                    w2f[ii][sp] = *(const short8*)(ws + w2off[ii * 3 + sp] + (unsigned)k0 * 2);
        }
        __syncthreads();

        // X fragments (all j, splits)
        short8 xf[NN][3];
        #pragma unroll
        for (int j = 0; j < NN; j++)
            #pragma unroll
            for (int sp = 0; sp < 3; sp++)
                xf[j][sp] = *(const short8*)(SB + xbyte + (j * 3 + sp) * 2048);

        // Y + U MFMAs (order identical to R2 for bitwise-stable accumulation)
#define YUP(IB_, NI_)                                                           \
        {                                                                       \
            _Pragma("unroll")                                                   \
            for (int ii = 0; ii < NI_; ii++) {                                  \
                const int i = IB_ + ii;                                         \
                const char* ap = SB + abyte + (i * 3) * 2048;                   \
                const short8 ah = *(const short8*)(ap);                         \
                const short8 am = *(const short8*)(ap + 2048);                  \
                const short8 al = *(const short8*)(ap + 4096);                  \
                _Pragma("unroll")                                               \
                for (int j = 0; j < NN; j++) {                                  \
                    f32x4 c = accY[ii][j];                                      \
                    c = MF(ah, xf[j][0], c);                                    \
                    c = MF(ah, xf[j][1], c);                                    \
                    c = MF(am, xf[j][0], c);                                    \
                    c = MF(am, xf[j][1], c);                                    \
                    c = MF(ah, xf[j][2], c);                                    \
                    c = MF(al, xf[j][0], c);                                    \
                    accY[ii][j] = c;                                            \
                }                                                               \
            }                                                                   \
            _Pragma("unroll")                                                   \
            for (int ii = 0; ii < NI_; ii++) {                                  \
                const int i = IB_ + ii;                                         \
                f32x4 u = accU[ii];                                             \
                u = MF(w2f[ii][0], xf[i][0], u);                                \
                u = MF(w2f[ii][0], xf[i][1], u);                                \
                u = MF(w2f[ii][1], xf[i][0], u);                                \
                u = MF(w2f[ii][1], xf[i][1], u);                                \
                u = MF(w2f[ii][0], xf[i][2], u);                                \
                u = MF(w2f[ii][2], xf[i][0], u);                                \
                accU[ii] = u;                                                   \
            }                                                                   \
        }
        if (iset == 0) { YUP(0, 2) } else { YUP(2, 3) }
    }

    // ---------------- epilogue (C/D: col=lane&15, row=qd*4+reg) ----------------
    const int sg  = s0 + 16 * sh + m_;
    const int og0 = o0 + 16 * oh + 4 * qd;

    float xe[NN][4];
    #pragma unroll
    for (int j = 0; j < NN; j++) {
        const float* px = x + (size_t)((j * BB + b) * CC + og0) * SSP + sg;
        #pragma unroll
        for (int r = 0; r < 4; r++) xe[j][r] = px[r * SSP];
    }

#define EPILOGUE(IB_, NI_)                                                      \
    {                                                                           \
        _Pragma("unroll")                                                       \
        for (int ii = 0; ii < NI_; ii++) {                                      \
            const int i = IB_ + ii;                                             \
            _Pragma("unroll")                                                   \
            for (int r = 0; r < 4; r++) {                                       \
                const float uu = accU[ii][r] + bias[i * CC + og0 + r];          \
                float e[NN]; float mx = 0.f;                                    \
                _Pragma("unroll")                                               \
                for (int j = 0; j < NN; j++) {                                  \
                    float d = fabsf(xe[j][r] - (accY[ii][j][r] + uu));          \
                    d = (d > THRESHV) ? d : 0.f;                                \
                    e[j] = d; mx = fmaxf(mx, d);                                \
                }                                                               \
                float sum = 0.f, hv = 0.f;                                      \
                _Pragma("unroll")                                               \
                for (int j = 0; j < NN; j++) {                                  \
                    const float p = __expf(e[j] - mx);                          \
                    sum += p; hv += p * xe[j][r];                               \
                }                                                               \
                out[(size_t)((i * BB + b) * CC + og0 + r) * SSP + sg] = hv / sum; \
            }                                                                   \
        }                                                                       \
    }
    if (iset == 0) { EPILOGUE(0, 2) } else { EPILOGUE(2, 3) }
}

// ================= fallback (R2 kernel, self-splitting) =================
static __device__ __forceinline__ void st4(unsigned short* p, unsigned short a,
                                           unsigned short b, unsigned short c, unsigned short d) {
    ushort4 v; v.x = a; v.y = b; v.z = c; v.w = d;
    *(ushort4*)p = v;
}
#define XB 15360
__global__ __launch_bounds__(512, 2)
void fub_mfma(const float* __restrict__ x, const float* __restrict__ w,
              const float* __restrict__ bias, float* __restrict__ out)
{
    __shared__ unsigned short S[30720];
    const int tid = threadIdx.x;
    const int b = blockIdx.z, o0 = blockIdx.y * 32, s0 = blockIdx.x * 32;
    const int lane = tid & 63, wv = tid >> 6;
    const int q = wv & 3, oh = q >> 1, sh = q & 1, iset = wv >> 2, qd = lane >> 4;
    const int sub = tid >> 8, t = tid & 255;
    const int wo = t >> 3, wkg = t & 7, xs = t & 31, xkq = t >> 5;
    const int wbase = wo * 32 + (((wkg >> 1) ^ ((wo >> 1) & 3)) << 3) + ((wkg & 1) << 2);
    const int xbase = xs * 32 + (((xkq >> 1) ^ ((xs >> 1) & 3)) << 3) + ((xkq & 1) << 2);
    const int ar = 16 * oh + (lane & 15), xr = 16 * sh + (lane & 15);
    const int asw8 = ((qd ^ ((ar >> 1) & 3)) << 3), xsw8 = ((qd ^ ((xr >> 1) & 3)) << 3);
    const int arow32 = ar * 32, xrow32 = xr * 32;
    f32x4 accY[3][5]; f32x4 accU[3];
    #pragma unroll
    for (int ii = 0; ii < 3; ii++) {
        accU[ii] = (f32x4){0.f, 0.f, 0.f, 0.f};
        #pragma unroll
        for (int j = 0; j < NN; j++) accY[ii][j] = (f32x4){0.f, 0.f, 0.f, 0.f};
    }
    float w2sav[3][4];
    #pragma unroll 1
    for (int k0 = 0; k0 < CC; k0 += 32) {
        if (k0) __syncthreads();
        #pragma unroll
        for (int rep = 0; rep < 3; rep++) {
            const int i = rep * 2 + sub;
            if (i < NN) {
                const float* gw = w + (size_t)(i * CC + o0 + wo) * (2 * CC) + k0 + wkg * 4;
                const float4 w1 = *(const float4*)gw;
                const float4 w2 = *(const float4*)(gw + CC);
                w2sav[rep][0] = w2.x; w2sav[rep][1] = w2.y; w2sav[rep][2] = w2.z; w2sav[rep][3] = w2.w;
                float av[4] = {w1.x + w2.x, w1.y + w2.y, w1.z + w2.z, w1.w + w2.w};
                unsigned short h[4], m[4], l[4];
                #pragma unroll
                for (int r = 0; r < 4; r++) split3(av[r], h[r], m[r], l[r]);
                unsigned short* p = &S[i * 3 * 1024 + wbase];
                st4(p, h[0], h[1], h[2], h[3]); st4(p + 1024, m[0], m[1], m[2], m[3]); st4(p + 2048, l[0], l[1], l[2], l[3]);
            }
        }
        #pragma unroll
        for (int rep = 0; rep < 3; rep++) {
            const int j = rep * 2 + sub;
            if (j < NN) {
                const float* gx = x + (size_t)((j * BB + b) * CC + k0 + xkq * 4) * SSP + s0 + xs;
                float v[4] = {gx[0], gx[SSP], gx[2 * SSP], gx[3 * SSP]};
                unsigned short h[4], m[4], l[4];
                #pragma unroll
                for (int r = 0; r < 4; r++) split3(v[r], h[r], m[r], l[r]);
                unsigned short* p = &S[XB + j * 3 * 1024 + xbase];
                st4(p, h[0], h[1], h[2], h[3]); st4(p + 1024, m[0], m[1], m[2], m[3]); st4(p + 2048, l[0], l[1], l[2], l[3]);
            }
        }
        __syncthreads();
        short8 xf[NN][3];
        #pragma unroll
        for (int j = 0; j < NN; j++)
            #pragma unroll
            for (int sp = 0; sp < 3; sp++)
                xf[j][sp] = *(const short8*)&S[XB + (j * 3 + sp) * 1024 + xrow32 + xsw8];
#define YPL(IB, NI_)                                                            \
        {                                                                       \
            _Pragma("unroll")                                                   \
            for (int ii = 0; ii < NI_; ii++) {                                  \
                const int i = IB + ii;                                          \
                const unsigned short* ap = &S[i * 3 * 1024 + arow32 + asw8];    \
                const short8 ah = *(const short8*)(ap);                         \
                const short8 am = *(const short8*)(ap + 1024);                  \
                const short8 al = *(const short8*)(ap + 2048);                  \
                _Pragma("unroll")                                               \
                for (int j = 0; j < NN; j++) {                                  \
                    f32x4 c = accY[ii][j];                                      \
                    c = MF(ah, xf[j][0], c); c = MF(ah, xf[j][1], c);           \
                    c = MF(am, xf[j][0], c); c = MF(am, xf[j][1], c);           \
                    c = MF(ah, xf[j][2], c); c = MF(al, xf[j][0], c);           \
                    accY[ii][j] = c;                                            \
                }                                                               \
            }                                                                   \
        }
        if (iset == 0) { YPL(0, 2) } else { YPL(2, 3) }
        __syncthreads();
        #pragma unroll
        for (int rep = 0; rep < 3; rep++) {
            const int i = rep * 2 + sub;
            if (i < NN) {
                unsigned short h[4], m[4], l[4];
                #pragma unroll
                for (int r = 0; r < 4; r++) split3(w2sav[rep][r], h[r], m[r], l[r]);
                unsigned short* p = &S[i * 3 * 1024 + wbase];
                st4(p, h[0], h[1], h[2], h[3]); st4(p + 1024, m[0], m[1], m[2], m[3]); st4(p + 2048, l[0], l[1], l[2], l[3]);
            }
        }
        __syncthreads();
#define UPL(IB, NI_)                                                            \
        {                                                                       \
            _Pragma("unroll")                                                   \
            for (int ii = 0; ii < NI_; ii++) {                                  \
                const int i = IB + ii;                                          \
                const unsigned short* wp = &S[i * 3 * 1024 + arow32 + asw8];    \
                const short8 wh = *(const short8*)(wp);                         \
                const short8 wm = *(const short8*)(wp + 1024);                  \
                const short8 wl = *(const short8*)(wp + 2048);                  \
                f32x4 u = accU[ii];                                             \
                u = MF(wh, xf[i][0], u); u = MF(wh, xf[i][1], u);               \
                u = MF(wm, xf[i][0], u); u = MF(wm, xf[i][1], u);               \
                u = MF(wh, xf[i][2], u); u = MF(wl, xf[i][0], u);               \
                accU[ii] = u;                                                   \
            }                                                                   \
        }
        if (iset == 0) { UPL(0, 2) } else { UPL(2, 3) }
    }
    const int sg = s0 + 16 * sh + (lane & 15);
    const int og0 = o0 + 16 * oh + 4 * qd;
    float xe[NN][4];
    #pragma unroll
    for (int j = 0; j < NN; j++) {
        const float* px = x + (size_t)((j * BB + b) * CC + og0) * SSP + sg;
        #pragma unroll
        for (int r = 0; r < 4; r++) xe[j][r] = px[r * SSP];
    }
    if (iset == 0) { EPILOGUE(0, 2) } else { EPILOGUE(2, 3) }
}

extern "C" void kernel_launch(void* const* d_in, const int* in_sizes, int n_in,
                              void* d_out, int out_size, void* d_ws, size_t ws_size,
                              hipStream_t stream) {
    const float* x      = (const float*)d_in[0];
    const float* conv_w = (const float*)d_in[1];
    const float* conv_b = (const float*)d_in[2];
    float* out = (float*)d_out;

    if (ws_size >= WS_NEED) {
        unsigned char* ws = (unsigned char*)d_ws;
        prep_w<<<160, 256, 0, stream>>>(conv_w, ws);
        prep_x<<<320, 256, 0, stream>>>(x, ws);
        fub_main<<<dim3(SSP / 32, CC / 32, BB), 512, 0, stream>>>(x, conv_b, ws, out);
    } else {
        fub_mfma<<<dim3(SSP / 32, CC / 32, BB), 512, 0, stream>>>(x, conv_w, conv_b, out);
    }
}

// Round 5
// 407.411 us; speedup vs baseline: 1.0748x; 1.0748x over previous
//
#include <hip/hip_runtime.h>
#include <math.h>

// N=5, B=8, C=256, H*W=1024
#define NN 5
#define CC 256
#define SSP 1024
#define BB 8
#define THRESHV 0.3f

typedef __attribute__((ext_vector_type(8))) short short8;   // 8 bf16 = one MFMA A/B frag
typedef __attribute__((ext_vector_type(4))) float f32x4;    // MFMA 16x16 accumulator

// ---------------- ws layout (bytes) ----------------
// X split planes, k-minor: [(j*8+b)*3+sp][s:1024][k:256] bf16
#define XW_OFF   0ull
#define XW_PLANE ((size_t)SSP * CC * 2)                 // 524288
#define XW_SIZE  ((size_t)NN * BB * 3 * XW_PLANE)       // 62,914,560
// A = W1+W2 split planes, k-minor: [i*3+sp][o:256][k:256]
#define AW_OFF   XW_SIZE
#define AW_PLANE ((size_t)CC * CC * 2)                  // 131072
#define AW_SIZE  ((size_t)NN * 3 * AW_PLANE)            // 1,966,080
#define W2_OFF   (AW_OFF + AW_SIZE)
#define WS_NEED  (W2_OFF + AW_SIZE)                     // ~63.8 MiB

// ---- exact 3-way bf16 split (Dekker-style; residuals exact in fp32) ----
static __device__ __forceinline__ unsigned short f2bf(float f) {
    unsigned int u = __builtin_bit_cast(unsigned int, f);
    u = u + 0x7fffu + ((u >> 16) & 1u);          // RNE to bf16
    return (unsigned short)(u >> 16);
}
static __device__ __forceinline__ float bf2f(unsigned short h) {
    unsigned int u = ((unsigned int)h) << 16;
    return __builtin_bit_cast(float, u);
}
static __device__ __forceinline__ void split3(float a, unsigned short& h,
                                              unsigned short& m, unsigned short& l) {
    h = f2bf(a); float r1 = a - bf2f(h);
    m = f2bf(r1); float r2 = r1 - bf2f(m);
    l = f2bf(r2);
}
static __device__ __forceinline__ f32x4 MF(short8 a, short8 b, f32x4 c) {
    return __builtin_amdgcn_mfma_f32_16x16x32_bf16(a, b, c, 0, 0, 0);
}

// async global->LDS, 16B per lane; LDS dest = uniform base + lane*16
#define GLD16(gp, lp) __builtin_amdgcn_global_load_lds(                          \
        (const __attribute__((address_space(1))) unsigned int*)(gp),             \
        (__attribute__((address_space(3))) unsigned int*)(lp), 16, 0, 0)

// ================= pre-pass: split weights =================
__global__ __launch_bounds__(256)
void prep_w(const float* __restrict__ w, unsigned char* __restrict__ ws) {
    const int id = blockIdx.x * 256 + threadIdx.x;   // 40960 = 5*256*32
    const int i  = id >> 13;
    const int o  = (id >> 5) & 255;
    const int ko = id & 31;                          // k-oct
    const float* gw = w + (size_t)(i * CC + o) * (2 * CC) + ko * 8;
    float av[8], wv[8];
    #pragma unroll
    for (int kk = 0; kk < 8; kk++) {
        wv[kk] = gw[CC + kk];
        av[kk] = gw[kk] + wv[kk];
    }
    unsigned short h[8], m[8], l[8];
    short8 H, M, L;
    #pragma unroll
    for (int kk = 0; kk < 8; kk++) split3(av[kk], h[kk], m[kk], l[kk]);
    #pragma unroll
    for (int kk = 0; kk < 8; kk++) { H[kk] = (short)h[kk]; M[kk] = (short)m[kk]; L[kk] = (short)l[kk]; }
    {
        unsigned char* p = ws + AW_OFF + (size_t)((i * 3) * CC + o) * 512 + ko * 16;
        *(short8*)(p)                = H;
        *(short8*)(p + CC * 512)     = M;
        *(short8*)(p + 2 * CC * 512) = L;
    }
    #pragma unroll
    for (int kk = 0; kk < 8; kk++) split3(wv[kk], h[kk], m[kk], l[kk]);
    #pragma unroll
    for (int kk = 0; kk < 8; kk++) { H[kk] = (short)h[kk]; M[kk] = (short)m[kk]; L[kk] = (short)l[kk]; }
    {
        unsigned char* p = ws + W2_OFF + (size_t)((i * 3) * CC + o) * 512 + ko * 16;
        *(short8*)(p)                = H;
        *(short8*)(p + CC * 512)     = M;
        *(short8*)(p + 2 * CC * 512) = L;
    }
}

// ================= pre-pass: split + transpose x (1280 blocks) ======
__global__ __launch_bounds__(256)
void prep_x(const float* __restrict__ x, unsigned char* __restrict__ ws) {
    const int blk = blockIdx.x;          // 1280 = 40 jb * 8 kc * 4 r
    const int r   = blk & 3;
    const int kc  = (blk >> 2) & 7;
    const int jb  = blk >> 5;            // j*8+b
    const int k0  = kc * 32;
    const int s   = threadIdx.x + 256 * r;
    const float* gx = x + ((size_t)jb * CC + k0) * SSP + s;
    unsigned char* w0 = ws + XW_OFF + (size_t)(jb * 3) * XW_PLANE
                      + (size_t)s * 512 + (size_t)k0 * 2;
    #pragma unroll
    for (int oct = 0; oct < 4; oct++) {
        float v[8];
        #pragma unroll
        for (int kk = 0; kk < 8; kk++) v[kk] = gx[(size_t)(oct * 8 + kk) * SSP];
        unsigned short h[8], m[8], l[8];
        #pragma unroll
        for (int kk = 0; kk < 8; kk++) split3(v[kk], h[kk], m[kk], l[kk]);
        short8 H, M, L;
        #pragma unroll
        for (int kk = 0; kk < 8; kk++) { H[kk] = (short)h[kk]; M[kk] = (short)m[kk]; L[kk] = (short)l[kk]; }
        *(short8*)(w0 + oct * 16)                 = H;
        *(short8*)(w0 + XW_PLANE + oct * 16)      = M;
        *(short8*)(w0 + 2 * XW_PLANE + oct * 16)  = L;
    }
}

// ================= main fused kernel (templated flavor) =================
// LDS: X planes only. 15 planes (j*3+sp) x 2048B. Bank swizzle carried in the
// per-lane DMA global address: within plane, unit = s*4 + (oct ^ (s&3) ^ ((s>>2)&3)).
// A and W2 fragments: direct global->register b128 from k-minor ws planes.
template<int IB, int NI>
__global__ __launch_bounds__(256, 3)
void fub_main(const float* __restrict__ x, const float* __restrict__ bias,
              const unsigned char* __restrict__ ws, float* __restrict__ out)
{
    __shared__ unsigned char SB[30720];

    const int tid  = threadIdx.x;
    const int b    = blockIdx.z;
    const int o0   = blockIdx.y * 32;
    const int s0   = blockIdx.x * 32;
    const int lane = tid & 63;
    const int w    = tid >> 6;            // wave 0..3 -> tile quarter
    const int oh   = w >> 1, sh = w & 1;
    const int qd   = lane >> 4;
    const int m_   = lane & 15;
    const int ar   = 16 * oh + m_;        // o row for A/W2 frags
    const int xr   = 16 * sh + m_;        // s row for X frags

    // ---- DMA staging: 30 slots over 4 waves (8,8,7,7); slot = sbase + t ----
    const int sbase = (w < 2) ? w * 8 : 16 + (w - 2) * 7;
    const int nsl   = (w < 2) ? 8 : 7;
    unsigned gOff[8];
    #pragma unroll
    for (int t = 0; t < 8; t++) {
        const int slot = sbase + t;
        const int p  = slot >> 1;              // plane 0..14 = j*3+sp
        const int jj = p / 3, sp = p - 3 * jj;
        const int u  = (slot & 1) * 64 + lane; // unit within plane
        const int sr = u >> 2;
        const int oc = (u & 3) ^ (sr & 3) ^ ((sr >> 2) & 3);
        gOff[t] = (unsigned)(((jj * BB + b) * 3 + sp) * XW_PLANE)
                + (unsigned)((s0 + sr) * 512 + oc * 16);
    }

    // ---- A/W2 frag per-lane base (k-minor planes) ----
    const unsigned vAW = (unsigned)AW_OFF + (unsigned)(o0 + ar) * 512u + (unsigned)qd * 16u;
    const unsigned vW2 = (unsigned)W2_OFF + (unsigned)(o0 + ar) * 512u + (unsigned)qd * 16u;
    // X frag LDS byte offset (within plane, swizzled)
    const unsigned xb = (unsigned)(xr * 4 + (qd ^ (xr & 3) ^ ((xr >> 2) & 3))) * 16u;

    f32x4 accY[NI][NN];
    f32x4 accU[NI];
    #pragma unroll
    for (int ii = 0; ii < NI; ii++) {
        accU[ii] = (f32x4){0.f, 0.f, 0.f, 0.f};
        #pragma unroll
        for (int j = 0; j < NN; j++) accY[ii][j] = (f32x4){0.f, 0.f, 0.f, 0.f};
    }

    #pragma unroll 1
    for (int k0 = 0; k0 < CC; k0 += 32) {
        if (k0) __syncthreads();
        // X staging DMA (swizzle carried in gaddr)
        #pragma unroll
        for (int t = 0; t < 8; t++) {
            if (t < nsl) {
                GLD16(ws + gOff[t], SB + (sbase + t) * 1024);
                gOff[t] += 64;
            }
        }
        // A frags for this chunk (global->reg; latency folds into the barrier drain)
        short8 af[NI][3];
        #pragma unroll
        for (int ii = 0; ii < NI; ii++)
            #pragma unroll
            for (int sp = 0; sp < 3; sp++)
                af[ii][sp] = *(const short8*)(ws + vAW
                    + (unsigned)(((IB + ii) * 3 + sp) * AW_PLANE) + (unsigned)k0 * 2);
        __syncthreads();

        // j-outer: X frags read once, shared across the i-set
        #pragma unroll
        for (int j = 0; j < NN; j++) {
            const unsigned char* xp = SB + (unsigned)(j * 3) * 2048u + xb;
            const short8 x0 = *(const short8*)(xp);
            const short8 x1 = *(const short8*)(xp + 2048);
            const short8 x2 = *(const short8*)(xp + 4096);
            #pragma unroll
            for (int ii = 0; ii < NI; ii++) {
                f32x4 c = accY[ii][j];
                c = MF(af[ii][0], x0, c);
                c = MF(af[ii][0], x1, c);
                c = MF(af[ii][1], x0, c);
                c = MF(af[ii][1], x1, c);
                c = MF(af[ii][0], x2, c);
                c = MF(af[ii][2], x0, c);
                accY[ii][j] = c;
            }
            if (j >= IB && j < IB + NI) {        // compile-time on unroll index
                constexpr int dummy = 0; (void)dummy;
                const int ui = j - IB;
                short8 w2f[3];
                #pragma unroll
                for (int sp = 0; sp < 3; sp++)
                    w2f[sp] = *(const short8*)(ws + vW2
                        + (unsigned)((j * 3 + sp) * AW_PLANE) + (unsigned)k0 * 2);
                f32x4 u = accU[ui];
                u = MF(w2f[0], x0, u);
                u = MF(w2f[0], x1, u);
                u = MF(w2f[1], x0, u);
                u = MF(w2f[1], x1, u);
                u = MF(w2f[0], x2, u);
                u = MF(w2f[2], x0, u);
                accU[ui] = u;
            }
        }
    }

    // ---------------- epilogue (C/D: col=lane&15, row=qd*4+reg) ----------------
    const int sg  = s0 + 16 * sh + m_;
    const int og0 = o0 + 16 * oh + 4 * qd;

    float xe[NN][4];
    #pragma unroll
    for (int j = 0; j < NN; j++) {
        const float* px = x + (size_t)((j * BB + b) * CC + og0) * SSP + sg;
        #pragma unroll
        for (int r = 0; r < 4; r++) xe[j][r] = px[r * SSP];
    }

    #pragma unroll
    for (int ii = 0; ii < NI; ii++) {
        const int i = IB + ii;
        #pragma unroll
        for (int r = 0; r < 4; r++) {
            const float uu = accU[ii][r] + bias[i * CC + og0 + r];
            float e[NN]; float mx = 0.f;
            #pragma unroll
            for (int j = 0; j < NN; j++) {
                float d = fabsf(xe[j][r] - (accY[ii][j][r] + uu));
                d = (d > THRESHV) ? d : 0.f;
                e[j] = d; mx = fmaxf(mx, d);
            }
            float sum = 0.f, hv = 0.f;
            #pragma unroll
            for (int j = 0; j < NN; j++) {
                const float p = __expf(e[j] - mx);
                sum += p; hv += p * xe[j][r];
            }
            out[(size_t)((i * BB + b) * CC + og0 + r) * SSP + sg] = hv / sum;
        }
    }
}

// ================= fallback (R2 kernel, self-splitting; known-good) ==========
static __device__ __forceinline__ void st4(unsigned short* p, unsigned short a,
                                           unsigned short b, unsigned short c, unsigned short d) {
    ushort4 v; v.x = a; v.y = b; v.z = c; v.w = d;
    *(ushort4*)p = v;
}
#define XB 15360
__global__ __launch_bounds__(512, 2)
void fub_mfma(const float* __restrict__ x, const float* __restrict__ w,
              const float* __restrict__ bias, float* __restrict__ out)
{
    __shared__ unsigned short S[30720];
    const int tid = threadIdx.x;
    const int b = blockIdx.z, o0 = blockIdx.y * 32, s0 = blockIdx.x * 32;
    const int lane = tid & 63, wv = tid >> 6;
    const int q = wv & 3, oh = q >> 1, sh = q & 1, iset = wv >> 2, qd = lane >> 4;
    const int sub = tid >> 8, t = tid & 255;
    const int wo = t >> 3, wkg = t & 7, xs = t & 31, xkq = t >> 5;
    const int wbase = wo * 32 + (((wkg >> 1) ^ ((wo >> 1) & 3)) << 3) + ((wkg & 1) << 2);
    const int xbase = xs * 32 + (((xkq >> 1) ^ ((xs >> 1) & 3)) << 3) + ((xkq & 1) << 2);
    const int ar = 16 * oh + (lane & 15), xr = 16 * sh + (lane & 15);
    const int asw8 = ((qd ^ ((ar >> 1) & 3)) << 3), xsw8 = ((qd ^ ((xr >> 1) & 3)) << 3);
    const int arow32 = ar * 32, xrow32 = xr * 32;
    f32x4 accY[3][5]; f32x4 accU[3];
    #pragma unroll
    for (int ii = 0; ii < 3; ii++) {
        accU[ii] = (f32x4){0.f, 0.f, 0.f, 0.f};
        #pragma unroll
        for (int j = 0; j < NN; j++) accY[ii][j] = (f32x4){0.f, 0.f, 0.f, 0.f};
    }
    float w2sav[3][4];
    #pragma unroll 1
    for (int k0 = 0; k0 < CC; k0 += 32) {
        if (k0) __syncthreads();
        #pragma unroll
        for (int rep = 0; rep < 3; rep++) {
            const int i = rep * 2 + sub;
            if (i < NN) {
                const float* gw = w + (size_t)(i * CC + o0 + wo) * (2 * CC) + k0 + wkg * 4;
                const float4 w1 = *(const float4*)gw;
                const float4 w2 = *(const float4*)(gw + CC);
                w2sav[rep][0] = w2.x; w2sav[rep][1] = w2.y; w2sav[rep][2] = w2.z; w2sav[rep][3] = w2.w;
                float av[4] = {w1.x + w2.x, w1.y + w2.y, w1.z + w2.z, w1.w + w2.w};
                unsigned short h[4], m[4], l[4];
                #pragma unroll
                for (int r = 0; r < 4; r++) split3(av[r], h[r], m[r], l[r]);
                unsigned short* p = &S[i * 3 * 1024 + wbase];
                st4(p, h[0], h[1], h[2], h[3]); st4(p + 1024, m[0], m[1], m[2], m[3]); st4(p + 2048, l[0], l[1], l[2], l[3]);
            }
        }
        #pragma unroll
        for (int rep = 0; rep < 3; rep++) {
            const int j = rep * 2 + sub;
            if (j < NN) {
                const float* gx = x + (size_t)((j * BB + b) * CC + k0 + xkq * 4) * SSP + s0 + xs;
                float v[4] = {gx[0], gx[SSP], gx[2 * SSP], gx[3 * SSP]};
                unsigned short h[4], m[4], l[4];
                #pragma unroll
                for (int r = 0; r < 4; r++) split3(v[r], h[r], m[r], l[r]);
                unsigned short* p = &S[XB + j * 3 * 1024 + xbase];
                st4(p, h[0], h[1], h[2], h[3]); st4(p + 1024, m[0], m[1], m[2], m[3]); st4(p + 2048, l[0], l[1], l[2], l[3]);
            }
        }
        __syncthreads();
        short8 xf[NN][3];
        #pragma unroll
        for (int j = 0; j < NN; j++)
            #pragma unroll
            for (int sp = 0; sp < 3; sp++)
                xf[j][sp] = *(const short8*)&S[XB + (j * 3 + sp) * 1024 + xrow32 + xsw8];
#define YPL(IB_, NI_)                                                           \
        {                                                                       \
            _Pragma("unroll")                                                   \
            for (int ii = 0; ii < NI_; ii++) {                                  \
                const int i = IB_ + ii;                                         \
                const unsigned short* ap = &S[i * 3 * 1024 + arow32 + asw8];    \
                const short8 ah = *(const short8*)(ap);                         \
                const short8 am = *(const short8*)(ap + 1024);                  \
                const short8 al = *(const short8*)(ap + 2048);                  \
                _Pragma("unroll")                                               \
                for (int j = 0; j < NN; j++) {                                  \
                    f32x4 c = accY[ii][j];                                      \
                    c = MF(ah, xf[j][0], c); c = MF(ah, xf[j][1], c);           \
                    c = MF(am, xf[j][0], c); c = MF(am, xf[j][1], c);           \
                    c = MF(ah, xf[j][2], c); c = MF(al, xf[j][0], c);           \
                    accY[ii][j] = c;                                            \
                }                                                               \
            }                                                                   \
        }
        if (iset == 0) { YPL(0, 2) } else { YPL(2, 3) }
        __syncthreads();
        #pragma unroll
        for (int rep = 0; rep < 3; rep++) {
            const int i = rep * 2 + sub;
            if (i < NN) {
                unsigned short h[4], m[4], l[4];
                #pragma unroll
                for (int r = 0; r < 4; r++) split3(w2sav[rep][r], h[r], m[r], l[r]);
                unsigned short* p = &S[i * 3 * 1024 + wbase];
                st4(p, h[0], h[1], h[2], h[3]); st4(p + 1024, m[0], m[1], m[2], m[3]); st4(p + 2048, l[0], l[1], l[2], l[3]);
            }
        }
        __syncthreads();
#define UPL(IB_, NI_)                                                           \
        {                                                                       \
            _Pragma("unroll")                                                   \
            for (int ii = 0; ii < NI_; ii++) {                                  \
                const int i = IB_ + ii;                                         \
                const unsigned short* wp = &S[i * 3 * 1024 + arow32 + asw8];    \
                const short8 wh = *(const short8*)(wp);                         \
                const short8 wm = *(const short8*)(wp + 1024);                  \
                const short8 wl = *(const short8*)(wp + 2048);                  \
                f32x4 u = accU[ii];                                             \
                u = MF(wh, xf[i][0], u); u = MF(wh, xf[i][1], u);               \
                u = MF(wm, xf[i][0], u); u = MF(wm, xf[i][1], u);               \
                u = MF(wh, xf[i][2], u); u = MF(wl, xf[i][0], u);               \
                accU[ii] = u;                                                   \
            }                                                                   \
        }
        if (iset == 0) { UPL(0, 2) } else { UPL(2, 3) }
    }
    const int sg = s0 + 16 * sh + (lane & 15);
    const int og0 = o0 + 16 * oh + 4 * qd;
    float xe[NN][4];
    #pragma unroll
    for (int j = 0; j < NN; j++) {
        const float* px = x + (size_t)((j * BB + b) * CC + og0) * SSP + sg;
        #pragma unroll
        for (int r = 0; r < 4; r++) xe[j][r] = px[r * SSP];
    }
#define EPI(IB_, NI_)                                                           \
    {                                                                           \
        _Pragma("unroll")                                                       \
        for (int ii = 0; ii < NI_; ii++) {                                      \
            const int i = IB_ + ii;                                             \
            _Pragma("unroll")                                                   \
            for (int r = 0; r < 4; r++) {                                       \
                const float uu = accU[ii][r] + bias[i * CC + og0 + r];          \
                float e[NN]; float mx = 0.f;                                    \
                _Pragma("unroll")                                               \
                for (int j = 0; j < NN; j++) {                                  \
                    float d = fabsf(xe[j][r] - (accY[ii][j][r] + uu));          \
                    d = (d > THRESHV) ? d : 0.f;                                \
                    e[j] = d; mx = fmaxf(mx, d);                                \
                }                                                               \
                float sum = 0.f, hv = 0.f;                                      \
                _Pragma("unroll")                                               \
                for (int j = 0; j < NN; j++) {                                  \
                    const float p = __expf(e[j] - mx);                          \
                    sum += p; hv += p * xe[j][r];                               \
                }                                                               \
                out[(size_t)((i * BB + b) * CC + og0 + r) * SSP + sg] = hv / sum; \
            }                                                                   \
        }                                                                       \
    }
    if (iset == 0) { EPI(0, 2) } else { EPI(2, 3) }
}

extern "C" void kernel_launch(void* const* d_in, const int* in_sizes, int n_in,
                              void* d_out, int out_size, void* d_ws, size_t ws_size,
                              hipStream_t stream) {
    const float* x      = (const float*)d_in[0];
    const float* conv_w = (const float*)d_in[1];
    const float* conv_b = (const float*)d_in[2];
    float* out = (float*)d_out;

    if (ws_size >= WS_NEED) {
        unsigned char* ws = (unsigned char*)d_ws;
        prep_w<<<160, 256, 0, stream>>>(conv_w, ws);
        prep_x<<<1280, 256, 0, stream>>>(x, ws);
        dim3 grid(SSP / 32, CC / 32, BB);   // 2048 blocks per flavor
        fub_main<0, 2><<<grid, 256, 0, stream>>>(x, conv_b, ws, out);
        fub_main<2, 3><<<grid, 256, 0, stream>>>(x, conv_b, ws, out);
    } else {
        fub_mfma<<<dim3(SSP / 32, CC / 32, BB), 512, 0, stream>>>(x, conv_w, conv_b, out);
    }
}